// Round 14
// baseline (2140.228 us; speedup 1.0000x reference)
//
#include <hip/hip_runtime.h>

#define DD 1024   // hidden size
#define MM 256    // random features
#define NN 16384  // hidden states
#define KK 8192   // weight rows

typedef float f32x4 __attribute__((ext_vector_type(4)));
typedef unsigned int u32x4 __attribute__((ext_vector_type(4)));
typedef unsigned int u32x2 __attribute__((ext_vector_type(2)));
typedef __bf16 bf16x8 __attribute__((ext_vector_type(8)));
typedef unsigned short u16;
typedef unsigned int u32;

static __device__ __forceinline__ u16 f2bf(float f) {
    u32 u = __builtin_bit_cast(u32, f);
    u32 r = u + 0x7fffu + ((u >> 16) & 1u);
    return (u16)(r >> 16);
}
static __device__ __forceinline__ float bf2f(u16 h) {
    u32 u = ((u32)h) << 16;
    return __builtin_bit_cast(float, u);
}

static __device__ __forceinline__ void gload_lds16(const void* g, void* l) {
    __builtin_amdgcn_global_load_lds(
        (const __attribute__((address_space(1))) u32*)g,
        (__attribute__((address_space(3))) u32*)l, 16, 0, 0);
}

static __device__ __forceinline__ bf16x8 ldfrag(const u16* p) {
    return __builtin_bit_cast(bf16x8, *(const u32x4*)p);
}

#define MFMA16(a, b, c) __builtin_amdgcn_mfma_f32_16x16x32_bf16((a), (b), (c), 0, 0, 0)

// ---------------------------------------------------------------------------
// INSTRUMENTATION ROUND: stage A body x20, stage B body x4 (idempotent reps)
// so both dispatches exceed the ~330us harness fills and appear in the
// rocprof top-5 with their counters. Next round reverts the rep loops.
// ---------------------------------------------------------------------------

// ---------------------------------------------------------------------------
// Kernel 1: omega fp32 -> (hi, lo) bf16 split   [R5 verbatim]
// ---------------------------------------------------------------------------
__global__ void k_conv(const float* __restrict__ om, u16* __restrict__ oh,
                       u16* __restrict__ ol) {
    int i = (blockIdx.x * blockDim.x + threadIdx.x) * 4;
    f32x4 x = *(const f32x4*)(om + i);
    ushort4 h, l;
    u16 t;
    t = f2bf(x.x); h.x = t; l.x = f2bf(x.x - bf2f(t));
    t = f2bf(x.y); h.y = t; l.y = f2bf(x.y - bf2f(t));
    t = f2bf(x.z); h.z = t; l.z = f2bf(x.z - bf2f(t));
    t = f2bf(x.w); h.w = t; l.w = f2bf(x.w - bf2f(t));
    *(ushort4*)(oh + i) = h;
    *(ushort4*)(ol + i) = l;
}

// ---------------------------------------------------------------------------
// Kernel 2: merged Stage A [R5 structure, body repeated REPA times]
// ---------------------------------------------------------------------------
#define REPA 20
__global__ __launch_bounds__(256, 4)
void k_stageA(const float* __restrict__ Hs, const float* __restrict__ Ws,
              const u16* __restrict__ Oh, const u16* __restrict__ Ol,
              u16* __restrict__ phiH, u16* __restrict__ phiW,
              float* __restrict__ emH, float* __restrict__ emW)
{
    __shared__ alignas(16) u16 Ah[32 * 32];
    __shared__ alignas(16) u16 Al[32 * 32];
    __shared__ alignas(16) u16 Bh[256 * 32];
    __shared__ alignas(16) u16 Bl[256 * 32];
    __shared__ float redmax[4][32];

    const int tid  = threadIdx.x;
    const int lane = tid & 63;
    const int wid  = tid >> 6;

    const float* __restrict__ X;
    u16* __restrict__ phi;
    float* __restrict__ em;
    int row0;
    if (blockIdx.x < NN / 32) {
        X = Hs; phi = phiH; em = emH; row0 = blockIdx.x * 32;
    } else {
        X = Ws; phi = phiW; em = emW; row0 = (blockIdx.x - NN / 32) * 32;
    }

    // A staging: thread loads float4 (row arow, fp32 cols acol..acol+3)
    const int arow = tid >> 3;           // 0..31
    const int acol = (tid & 7) * 4;      // 0,4,..,28
    const float* __restrict__ xrow = X + (long)(row0 + arow) * DD;
    const int a_idx = arow * 32 + (acol ^ (((arow >> 1) & 3) << 3));

    const int r16 = lane & 15;
    const int h8  = (lane >> 4) << 3;
    int aoffs[2], boffs[4];
#pragma unroll
    for (int m = 0; m < 2; ++m) {
        int row = m * 16 + r16;
        aoffs[m] = row * 32 + (h8 ^ (((row >> 1) & 3) << 3));
    }
#pragma unroll
    for (int n = 0; n < 4; ++n) {
        int row = wid * 64 + n * 16 + r16;
        boffs[n] = row * 32 + (h8 ^ (((row >> 1) & 3) << 3));
    }

    for (int rep = 0; rep < REPA; ++rep) {
        f32x4 acc[2][4];
#pragma unroll
        for (int m = 0; m < 2; ++m)
#pragma unroll
            for (int n = 0; n < 4; ++n) acc[m][n] = f32x4{0.f, 0.f, 0.f, 0.f};

        for (int ks = 0; ks < DD / 32; ++ks) {
            const int k0 = ks * 32;
#pragma unroll
            for (int s = 0; s < 4; ++s) {
                const int c    = s * 256 + tid;
                const int brow = c >> 2;
                const int scol = k0 + (((c & 3) << 3) ^ (((brow >> 1) & 3) << 3));
                gload_lds16(Oh + brow * DD + scol, Bh + (s * 256 + wid * 64) * 8);
                gload_lds16(Ol + brow * DD + scol, Bl + (s * 256 + wid * 64) * 8);
            }
            f32x4 x = *(const f32x4*)(xrow + k0 + acol);
            u32x2 ph, pl;
#pragma unroll
            for (int j = 0; j < 2; ++j) {
                u16 h0 = f2bf(x[2 * j]);
                u16 h1 = f2bf(x[2 * j + 1]);
                u16 l0 = f2bf(x[2 * j] - bf2f(h0));
                u16 l1 = f2bf(x[2 * j + 1] - bf2f(h1));
                ph[j] = (u32)h0 | ((u32)h1 << 16);
                pl[j] = (u32)l0 | ((u32)l1 << 16);
            }
            *(u32x2*)(Ah + a_idx) = ph;
            *(u32x2*)(Al + a_idx) = pl;
            __syncthreads();

            bf16x8 fah[2], fal[2], fbh[4], fbl[4];
#pragma unroll
            for (int m = 0; m < 2; ++m) {
                fah[m] = ldfrag(Ah + aoffs[m]);
                fal[m] = ldfrag(Al + aoffs[m]);
            }
#pragma unroll
            for (int n = 0; n < 4; ++n) {
                fbh[n] = ldfrag(Bh + boffs[n]);
                fbl[n] = ldfrag(Bl + boffs[n]);
            }
#pragma unroll
            for (int m = 0; m < 2; ++m)
#pragma unroll
                for (int n = 0; n < 4; ++n) {
                    acc[m][n] = MFMA16(fah[m], fbh[n], acc[m][n]);
                    acc[m][n] = MFMA16(fah[m], fbl[n], acc[m][n]);
                    acc[m][n] = MFMA16(fal[m], fbh[n], acc[m][n]);
                }
            __syncthreads();
        }

#pragma unroll
        for (int m = 0; m < 2; ++m) {
#pragma unroll
            for (int i = 0; i < 4; ++i) {
                float v = fmaxf(fmaxf(acc[m][0][i], acc[m][1][i]),
                                fmaxf(acc[m][2][i], acc[m][3][i]));
                v = fmaxf(v, __shfl_xor(v, 1));
                v = fmaxf(v, __shfl_xor(v, 2));
                v = fmaxf(v, __shfl_xor(v, 4));
                v = fmaxf(v, __shfl_xor(v, 8));
                if (r16 == 0) redmax[wid][m * 16 + ((lane >> 4) << 2) + i] = v;
            }
        }
        __syncthreads();
        if (tid < 32) {
            float fm = fmaxf(fmaxf(redmax[0][tid], redmax[1][tid]),
                             fmaxf(redmax[2][tid], redmax[3][tid]));
            em[row0 + tid] = __expf(fminf(fmaxf(-fm, -87.f), 87.f));
        }
#pragma unroll
        for (int m = 0; m < 2; ++m) {
#pragma unroll
            for (int i = 0; i < 4; ++i) {
                const int rl = m * 16 + ((lane >> 4) << 2) + i;
                const float fm = fmaxf(fmaxf(redmax[0][rl], redmax[1][rl]),
                                       fmaxf(redmax[2][rl], redmax[3][rl]));
#pragma unroll
                for (int n = 0; n < 4; ++n) {
                    float p   = acc[m][n][i];
                    float ph_ = (__expf(p - fm) + 1e-6f) * 0.0625f;
                    phi[(long)(row0 + rl) * MM + wid * 64 + n * 16 + r16] = f2bf(ph_);
                }
            }
        }
        __syncthreads();   // rep boundary: phi/redmax reads done before reuse
    }
}

// ---------------------------------------------------------------------------
// Kernel 3: Stage B [R11 structure, body repeated REPB times]
// ---------------------------------------------------------------------------
#define REPB 4
__global__ __launch_bounds__(256, 4)
void k_stageB(const u16* __restrict__ PH, const u16* __restrict__ PW,
              const float* __restrict__ EH, const float* __restrict__ EW,
              float* __restrict__ out)
{
    __shared__ alignas(16) unsigned char smem_raw[64 * 130 * 4];
    u16* const As = (u16*)smem_raw;
    u16* const Bs = As + 128 * 64;
    float* const ftile = (float*)smem_raw;
    const int FST = 130;

    const int tid  = threadIdx.x;
    const int lane = tid & 63;
    const int wid  = tid >> 6;
    const int bm   = blockIdx.x >> 6;   // 0..127
    const int bn   = blockIdx.x & 63;   // 0..63
    const int row0 = bm * 128, col0 = bn * 128;
    const int wr   = wid >> 1, wc = wid & 1;
    const int r16  = lane & 15;
    const int h8   = (lane >> 4) << 3;

    int aoffs[2][4], boffs[2][4];
#pragma unroll
    for (int sl = 0; sl < 2; ++sl) {
#pragma unroll
        for (int m = 0; m < 4; ++m) {
            int row = wr * 64 + m * 16 + r16;
            aoffs[sl][m] = row * 64 + (((((sl * 32 + h8) << 1)) ^ ((row & 7) << 4)) >> 1);
        }
#pragma unroll
        for (int n = 0; n < 4; ++n) {
            int row = wc * 64 + n * 16 + r16;
            boffs[sl][n] = row * 64 + (((((sl * 32 + h8) << 1)) ^ ((row & 7) << 4)) >> 1);
        }
    }

    float ew_[4];
#pragma unroll
    for (int n = 0; n < 4; ++n) ew_[n] = EW[col0 + wc * 64 + n * 16 + r16];

    for (int rep = 0; rep < REPB; ++rep) {
        // rep boundary WAR: prior rep's ftile ds_reads must retire before
        // gload_lds overwrites the union'd smem
        asm volatile("s_waitcnt lgkmcnt(0)" ::: "memory");
        __builtin_amdgcn_s_barrier();

        f32x4 acc[4][4];
#pragma unroll
        for (int m = 0; m < 4; ++m)
#pragma unroll
            for (int n = 0; n < 4; ++n) acc[m][n] = f32x4{0.f, 0.f, 0.f, 0.f};

        for (int ks = 0; ks < 4; ++ks) {
            const int k0 = ks * 64;
#pragma unroll
            for (int s = 0; s < 4; ++s) {
                const int c    = s * 256 + tid;
                const int row  = c >> 3;
                const int cbl  = ((c & 7) << 4) ^ ((row & 7) << 4);
                const int scol = k0 + (cbl >> 1);
                gload_lds16(PH + (long)(row0 + row) * MM + scol, As + (s * 256 + wid * 64) * 8);
                gload_lds16(PW + (long)(col0 + row) * MM + scol, Bs + (s * 256 + wid * 64) * 8);
            }
            __syncthreads();
#pragma unroll
            for (int sl = 0; sl < 2; ++sl) {
                bf16x8 fa[4], fb[4];
#pragma unroll
                for (int m = 0; m < 4; ++m) fa[m] = ldfrag(As + aoffs[sl][m]);
#pragma unroll
                for (int n = 0; n < 4; ++n) fb[n] = ldfrag(Bs + boffs[sl][n]);
#pragma unroll
                for (int m = 0; m < 4; ++m)
#pragma unroll
                    for (int n = 0; n < 4; ++n)
                        acc[m][n] = MFMA16(fa[m], fb[n], acc[m][n]);
            }
            __syncthreads();
        }

#pragma unroll
        for (int mm = 0; mm < 2; ++mm) {
            if (mm == 1) {
                asm volatile("s_waitcnt lgkmcnt(0)" ::: "memory");
                __builtin_amdgcn_s_barrier();
            }
#pragma unroll
            for (int ms = 0; ms < 2; ++ms) {
                const int m = 2 * mm + ms;
#pragma unroll
                for (int i = 0; i < 4; ++i) {
                    const int lr   = wr * 32 + ms * 16 + ((lane >> 4) << 2) + i;
                    const int grow = row0 + wr * 64 + m * 16 + ((lane >> 4) << 2) + i;
                    const float eh = EH[grow];
#pragma unroll
                    for (int n = 0; n < 4; ++n) {
                        float rf = acc[m][n][i] + 1e-10f;
                        float t  = eh * ew_[n];
                        float o  = rf * __builtin_amdgcn_rcpf(rf + t);
                        ftile[lr * FST + wc * 64 + n * 16 + r16] = o;
                    }
                }
            }
            asm volatile("s_waitcnt lgkmcnt(0)" ::: "memory");
            __builtin_amdgcn_s_barrier();
#pragma unroll
            for (int p = 0; p < 8; ++p) {
                const int r = p * 8 + (tid >> 5);
                const int c = (tid & 31) * 4;
                f32x4 v = *(const f32x4*)&ftile[r * FST + c];
                const int grow = row0 + (r >> 5) * 64 + (2 * mm + ((r >> 4) & 1)) * 16 + (r & 15);
                __builtin_nontemporal_store(
                    v, (f32x4*)(out + (long)grow * KK + col0 + c));
            }
        }
    }
}

// ---------------------------------------------------------------------------
extern "C" void kernel_launch(void* const* d_in, const int* in_sizes, int n_in,
                              void* d_out, int out_size, void* d_ws, size_t ws_size,
                              hipStream_t stream) {
    (void)in_sizes; (void)n_in; (void)out_size; (void)ws_size;
    const float* H  = (const float*)d_in[0];
    const float* W  = (const float*)d_in[1];
    const float* Om = (const float*)d_in[2];
    float* out = (float*)d_out;

    char* ws   = (char*)d_ws;
    u16*  phiH = (u16*)ws;                                       // 8 MB
    u16*  phiW = (u16*)(ws + (size_t)NN * MM * 2);               // 4 MB
    float* emh = (float*)(ws + (size_t)(NN + KK) * MM * 2);      // 64 KB
    float* emw = emh + NN;                                       // 32 KB
    u16*  oh   = (u16*)(emw + KK);                               // 512 KB
    u16*  ol   = oh + MM * DD;                                   // 512 KB

    k_conv<<<(MM * DD) / 1024, 256, 0, stream>>>(Om, oh, ol);
    k_stageA<<<(NN + KK) / 32, 256, 0, stream>>>(H, W, oh, ol, phiH, phiW, emh, emw);
    k_stageB<<<(NN / 128) * (KK / 128), 256, 0, stream>>>(phiH, phiW, emh, emw, out);
}

// Round 15
// 241.545 us; speedup vs baseline: 8.8606x; 8.8606x over previous
//
#include <hip/hip_runtime.h>

#define DD 1024   // hidden size
#define MM 256    // random features
#define NN 16384  // hidden states
#define KK 8192   // weight rows

typedef float f32x4 __attribute__((ext_vector_type(4)));
typedef unsigned int u32x4 __attribute__((ext_vector_type(4)));
typedef unsigned int u32x2 __attribute__((ext_vector_type(2)));
typedef __bf16 bf16x8 __attribute__((ext_vector_type(8)));
typedef unsigned short u16;
typedef unsigned int u32;

static __device__ __forceinline__ u16 f2bf(float f) {
    u32 u = __builtin_bit_cast(u32, f);
    u32 r = u + 0x7fffu + ((u >> 16) & 1u);
    return (u16)(r >> 16);
}
static __device__ __forceinline__ float bf2f(u16 h) {
    u32 u = ((u32)h) << 16;
    return __builtin_bit_cast(float, u);
}

static __device__ __forceinline__ void gload_lds16(const void* g, void* l) {
    __builtin_amdgcn_global_load_lds(
        (const __attribute__((address_space(1))) u32*)g,
        (__attribute__((address_space(3))) u32*)l, 16, 0, 0);
}

static __device__ __forceinline__ bf16x8 ldfrag(const u16* p) {
    return __builtin_bit_cast(bf16x8, *(const u32x4*)p);
}

#define MFMA16(a, b, c) __builtin_amdgcn_mfma_f32_16x16x32_bf16((a), (b), (c), 0, 0, 0)

// ---------------------------------------------------------------------------
// Kernel 1: omega fp32 -> (hi, lo) bf16 split   [R5 verbatim]
// ---------------------------------------------------------------------------
__global__ void k_conv(const float* __restrict__ om, u16* __restrict__ oh,
                       u16* __restrict__ ol) {
    int i = (blockIdx.x * blockDim.x + threadIdx.x) * 4;
    f32x4 x = *(const f32x4*)(om + i);
    ushort4 h, l;
    u16 t;
    t = f2bf(x.x); h.x = t; l.x = f2bf(x.x - bf2f(t));
    t = f2bf(x.y); h.y = t; l.y = f2bf(x.y - bf2f(t));
    t = f2bf(x.z); h.z = t; l.z = f2bf(x.z - bf2f(t));
    t = f2bf(x.w); h.w = t; l.w = f2bf(x.w - bf2f(t));
    *(ushort4*)(oh + i) = h;
    *(ushort4*)(ol + i) = l;
}

// ---------------------------------------------------------------------------
// Kernel 2: Stage A v2 — proj = X @ Omega^T, split-bf16 (3 MFMA products).
// NO LDS, NO BARRIERS in the K-loop (R14 counters: all pipes <=25%, the
// barrier-drained L2 latency was the cost). Each wave loads its B (Omega)
// fragments DIRECTLY from L2 to registers — the 16B at Omega[row][k0+h8..+7]
// IS the bf16x8 fragment, no conversion. A loaded direct from X with
// in-register hi/lo split. Depth-1 register ping-pong prefetch; compiler
// inserts counted vmcnt on register deps. Cross-wave sync only in the final
// rowmax reduction (512B LDS + 2 barriers). 32 rows/block, 768 blocks,
// ~155 VGPR -> 3 waves/SIMD (12 waves/CU, all free-running).
// ---------------------------------------------------------------------------
__global__ __launch_bounds__(256, 3)
void k_stageA(const float* __restrict__ Hs, const float* __restrict__ Ws,
              const u16* __restrict__ Oh, const u16* __restrict__ Ol,
              u16* __restrict__ phiH, u16* __restrict__ phiW,
              float* __restrict__ emH, float* __restrict__ emW)
{
    __shared__ float redmax[4][32];

    const int tid  = threadIdx.x;
    const int lane = tid & 63;
    const int wid  = tid >> 6;
    const int r16  = lane & 15;
    const int h8   = (lane >> 4) << 3;

    const float* __restrict__ X;
    u16* __restrict__ phi;
    float* __restrict__ em;
    int row0;
    if (blockIdx.x < NN / 32) {
        X = Hs; phi = phiH; em = emH; row0 = blockIdx.x * 32;
    } else {
        X = Ws; phi = phiW; em = emW; row0 = (blockIdx.x - NN / 32) * 32;
    }

    f32x4 acc[2][4];
#pragma unroll
    for (int m = 0; m < 2; ++m)
#pragma unroll
        for (int n = 0; n < 4; ++n) acc[m][n] = f32x4{0.f, 0.f, 0.f, 0.f};

    // single per-lane bases + uniform offsets (keeps address VGPRs low)
    const u16*  obh = Oh + (long)(wid * 64 + r16) * DD + h8;
    const u16*  obl = Ol + (long)(wid * 64 + r16) * DD + h8;
    const float* xb = X + (long)(row0 + r16) * DD + h8;

    u32x4 bh0[4], bl0[4], bh1[4], bl1[4];
    f32x4 ax0[2][2], ax1[2][2];

    auto load = [&](int k0, u32x4 (&bh)[4], u32x4 (&bl)[4], f32x4 (&ax)[2][2]) {
#pragma unroll
        for (int n = 0; n < 4; ++n) {
            bh[n] = *(const u32x4*)(obh + n * 16 * DD + k0);
            bl[n] = *(const u32x4*)(obl + n * 16 * DD + k0);
        }
#pragma unroll
        for (int m = 0; m < 2; ++m) {
            ax[m][0] = *(const f32x4*)(xb + m * 16 * DD + k0);
            ax[m][1] = *(const f32x4*)(xb + m * 16 * DD + k0 + 4);
        }
    };
    auto compute = [&](u32x4 (&bh)[4], u32x4 (&bl)[4], f32x4 (&ax)[2][2]) {
        bf16x8 fah[2], fal[2];
#pragma unroll
        for (int m = 0; m < 2; ++m) {
            const float e[8] = {ax[m][0][0], ax[m][0][1], ax[m][0][2], ax[m][0][3],
                                ax[m][1][0], ax[m][1][1], ax[m][1][2], ax[m][1][3]};
            u32x4 ph, pl;
#pragma unroll
            for (int j = 0; j < 4; ++j) {
                u16 a0 = f2bf(e[2 * j]);
                u16 a1 = f2bf(e[2 * j + 1]);
                u16 c0 = f2bf(e[2 * j] - bf2f(a0));
                u16 c1 = f2bf(e[2 * j + 1] - bf2f(a1));
                ph[j] = (u32)a0 | ((u32)a1 << 16);
                pl[j] = (u32)c0 | ((u32)c1 << 16);
            }
            fah[m] = __builtin_bit_cast(bf16x8, ph);
            fal[m] = __builtin_bit_cast(bf16x8, pl);
        }
#pragma unroll
        for (int m = 0; m < 2; ++m)
#pragma unroll
            for (int n = 0; n < 4; ++n) {
                acc[m][n] = MFMA16(fah[m], __builtin_bit_cast(bf16x8, bh[n]), acc[m][n]);
                acc[m][n] = MFMA16(fah[m], __builtin_bit_cast(bf16x8, bl[n]), acc[m][n]);
                acc[m][n] = MFMA16(fal[m], __builtin_bit_cast(bf16x8, bh[n]), acc[m][n]);
            }
    };

    // depth-1 ping-pong: load k+1 issued before compute k consumes its regs
    load(0, bh0, bl0, ax0);
    for (int ks = 0; ks < 32; ks += 2) {
        load((ks + 1) * 32, bh1, bl1, ax1);
        compute(bh0, bl0, ax0);
        if (ks + 2 < 32) load((ks + 2) * 32, bh0, bl0, ax0);
        compute(bh1, bl1, ax1);
    }

    // row max: lane-local over n, across 16 lanes sharing a row, then
    // across the 4 waves' column slices (first and only barriers)
#pragma unroll
    for (int m = 0; m < 2; ++m) {
#pragma unroll
        for (int i = 0; i < 4; ++i) {
            float v = fmaxf(fmaxf(acc[m][0][i], acc[m][1][i]),
                            fmaxf(acc[m][2][i], acc[m][3][i]));
            v = fmaxf(v, __shfl_xor(v, 1));
            v = fmaxf(v, __shfl_xor(v, 2));
            v = fmaxf(v, __shfl_xor(v, 4));
            v = fmaxf(v, __shfl_xor(v, 8));
            if (r16 == 0) redmax[wid][m * 16 + ((lane >> 4) << 2) + i] = v;
        }
    }
    __syncthreads();
    if (tid < 32) {
        float fm = fmaxf(fmaxf(redmax[0][tid], redmax[1][tid]),
                         fmaxf(redmax[2][tid], redmax[3][tid]));
        // em = exp(-clamp(max)) so stage B epilogue needs no log/exp
        em[row0 + tid] = __expf(fminf(fmaxf(-fm, -87.f), 87.f));
    }
#pragma unroll
    for (int m = 0; m < 2; ++m) {
#pragma unroll
        for (int i = 0; i < 4; ++i) {
            const int rl = m * 16 + ((lane >> 4) << 2) + i;
            const float fm = fmaxf(fmaxf(redmax[0][rl], redmax[1][rl]),
                                   fmaxf(redmax[2][rl], redmax[3][rl]));
#pragma unroll
            for (int n = 0; n < 4; ++n) {
                float p   = acc[m][n][i];
                float ph_ = (__expf(p - fm) + 1e-6f) * 0.0625f;
                phi[(long)(row0 + rl) * MM + wid * 64 + n * 16 + r16] = f2bf(ph_);
            }
        }
    }
}

// ---------------------------------------------------------------------------
// Kernel 3: Stage B — rf = phi_h @ phi_w^T (K=256), epilogue
//   out = rf' / (rf' + eh*ew),  rf' = rf + 1e-10
// [R11 verbatim — 103us vs 81us write floor; scheduling theories exhausted]
// ---------------------------------------------------------------------------
__global__ __launch_bounds__(256, 4)
void k_stageB(const u16* __restrict__ PH, const u16* __restrict__ PW,
              const float* __restrict__ EH, const float* __restrict__ EW,
              float* __restrict__ out)
{
    // union: K-loop staging (32 KB) | epilogue f32 tile 64x130 (33.28 KB)
    __shared__ alignas(16) unsigned char smem_raw[64 * 130 * 4];
    u16* const As = (u16*)smem_raw;
    u16* const Bs = As + 128 * 64;
    float* const ftile = (float*)smem_raw;
    const int FST = 130;

    const int tid  = threadIdx.x;
    const int lane = tid & 63;
    const int wid  = tid >> 6;
    const int bm   = blockIdx.x >> 6;   // 0..127
    const int bn   = blockIdx.x & 63;   // 0..63
    const int row0 = bm * 128, col0 = bn * 128;
    const int wr   = wid >> 1, wc = wid & 1;
    const int r16  = lane & 15;
    const int h8   = (lane >> 4) << 3;

    f32x4 acc[4][4];
#pragma unroll
    for (int m = 0; m < 4; ++m)
#pragma unroll
        for (int n = 0; n < 4; ++n) acc[m][n] = f32x4{0.f, 0.f, 0.f, 0.f};

    int aoffs[2][4], boffs[2][4];
#pragma unroll
    for (int sl = 0; sl < 2; ++sl) {
#pragma unroll
        for (int m = 0; m < 4; ++m) {
            int row = wr * 64 + m * 16 + r16;
            aoffs[sl][m] = row * 64 + (((((sl * 32 + h8) << 1)) ^ ((row & 7) << 4)) >> 1);
        }
#pragma unroll
        for (int n = 0; n < 4; ++n) {
            int row = wc * 64 + n * 16 + r16;
            boffs[sl][n] = row * 64 + (((((sl * 32 + h8) << 1)) ^ ((row & 7) << 4)) >> 1);
        }
    }

    for (int ks = 0; ks < 4; ++ks) {
        const int k0 = ks * 64;
#pragma unroll
        for (int s = 0; s < 4; ++s) {
            const int c    = s * 256 + tid;
            const int row  = c >> 3;
            const int cbl  = ((c & 7) << 4) ^ ((row & 7) << 4);
            const int scol = k0 + (cbl >> 1);
            gload_lds16(PH + (long)(row0 + row) * MM + scol, As + (s * 256 + wid * 64) * 8);
            gload_lds16(PW + (long)(col0 + row) * MM + scol, Bs + (s * 256 + wid * 64) * 8);
        }
        __syncthreads();
#pragma unroll
        for (int sl = 0; sl < 2; ++sl) {
            bf16x8 fa[4], fb[4];
#pragma unroll
            for (int m = 0; m < 4; ++m) fa[m] = ldfrag(As + aoffs[sl][m]);
#pragma unroll
            for (int n = 0; n < 4; ++n) fb[n] = ldfrag(Bs + boffs[sl][n]);
#pragma unroll
            for (int m = 0; m < 4; ++m)
#pragma unroll
                for (int n = 0; n < 4; ++n)
                    acc[m][n] = MFMA16(fa[m], fb[n], acc[m][n]);
        }
        __syncthreads();
    }
    // K-loop's final __syncthreads drained everything: As/Bs reads retired.

    // epilogue: out = rf' / (rf' + eh*ew). 2 passes of 64 rows; LDS-only
    // synchronization (lgkmcnt + raw s_barrier) -> NT stores never drained.
    float ew_[4];
#pragma unroll
    for (int n = 0; n < 4; ++n) ew_[n] = EW[col0 + wc * 64 + n * 16 + r16];

#pragma unroll
    for (int mm = 0; mm < 2; ++mm) {
        if (mm == 1) {
            asm volatile("s_waitcnt lgkmcnt(0)" ::: "memory");
            __builtin_amdgcn_s_barrier();
        }
#pragma unroll
        for (int ms = 0; ms < 2; ++ms) {
            const int m = 2 * mm + ms;
#pragma unroll
            for (int i = 0; i < 4; ++i) {
                const int lr   = wr * 32 + ms * 16 + ((lane >> 4) << 2) + i; // 0..63
                const int grow = row0 + wr * 64 + m * 16 + ((lane >> 4) << 2) + i;
                const float eh = EH[grow];
#pragma unroll
                for (int n = 0; n < 4; ++n) {
                    float rf = acc[m][n][i] + 1e-10f;
                    float t  = eh * ew_[n];
                    float o  = rf * __builtin_amdgcn_rcpf(rf + t);
                    ftile[lr * FST + wc * 64 + n * 16 + r16] = o;
                }
            }
        }
        asm volatile("s_waitcnt lgkmcnt(0)" ::: "memory");
        __builtin_amdgcn_s_barrier();
#pragma unroll
        for (int p = 0; p < 8; ++p) {
            const int r = p * 8 + (tid >> 5);        // 0..63 local row
            const int c = (tid & 31) * 4;            // 0..124
            f32x4 v = *(const f32x4*)&ftile[r * FST + c];
            const int grow = row0 + (r >> 5) * 64 + (2 * mm + ((r >> 4) & 1)) * 16 + (r & 15);
            __builtin_nontemporal_store(
                v, (f32x4*)(out + (long)grow * KK + col0 + c));
        }
    }
}

// ---------------------------------------------------------------------------
extern "C" void kernel_launch(void* const* d_in, const int* in_sizes, int n_in,
                              void* d_out, int out_size, void* d_ws, size_t ws_size,
                              hipStream_t stream) {
    (void)in_sizes; (void)n_in; (void)out_size; (void)ws_size;
    const float* H  = (const float*)d_in[0];
    const float* W  = (const float*)d_in[1];
    const float* Om = (const float*)d_in[2];
    float* out = (float*)d_out;

    char* ws   = (char*)d_ws;
    u16*  phiH = (u16*)ws;                                       // 8 MB
    u16*  phiW = (u16*)(ws + (size_t)NN * MM * 2);               // 4 MB
    float* emh = (float*)(ws + (size_t)(NN + KK) * MM * 2);      // 64 KB
    float* emw = emh + NN;                                       // 32 KB
    u16*  oh   = (u16*)(emw + KK);                               // 512 KB
    u16*  ol   = oh + MM * DD;                                   // 512 KB

    k_conv<<<(MM * DD) / 1024, 256, 0, stream>>>(Om, oh, ol);
    k_stageA<<<(NN + KK) / 32, 256, 0, stream>>>(H, W, oh, ol, phiH, phiW, emh, emw);
    k_stageB<<<(NN / 128) * (KK / 128), 256, 0, stream>>>(phiH, phiW, emh, emw, out);
}

// Round 16
// 179.176 us; speedup vs baseline: 11.9448x; 1.3481x over previous
//
#include <hip/hip_runtime.h>

#define DD 1024   // hidden size
#define MM 256    // random features
#define NN 16384  // hidden states
#define KK 8192   // weight rows

typedef float f32x4 __attribute__((ext_vector_type(4)));
typedef unsigned int u32x4 __attribute__((ext_vector_type(4)));
typedef unsigned int u32x2 __attribute__((ext_vector_type(2)));
typedef __bf16 bf16x8 __attribute__((ext_vector_type(8)));
typedef unsigned short u16;
typedef unsigned int u32;

static __device__ __forceinline__ u16 f2bf(float f) {
    u32 u = __builtin_bit_cast(u32, f);
    u32 r = u + 0x7fffu + ((u >> 16) & 1u);
    return (u16)(r >> 16);
}
static __device__ __forceinline__ float bf2f(u16 h) {
    u32 u = ((u32)h) << 16;
    return __builtin_bit_cast(float, u);
}

static __device__ __forceinline__ void gload_lds16(const void* g, void* l) {
    __builtin_amdgcn_global_load_lds(
        (const __attribute__((address_space(1))) u32*)g,
        (__attribute__((address_space(3))) u32*)l, 16, 0, 0);
}

static __device__ __forceinline__ bf16x8 ldfrag(const u16* p) {
    return __builtin_bit_cast(bf16x8, *(const u32x4*)p);
}

#define MFMA16(a, b, c) __builtin_amdgcn_mfma_f32_16x16x32_bf16((a), (b), (c), 0, 0, 0)

// ---------------------------------------------------------------------------
// Kernel 1: omega fp32 -> (hi, lo) bf16 split   [R5 verbatim]
// ---------------------------------------------------------------------------
__global__ void k_conv(const float* __restrict__ om, u16* __restrict__ oh,
                       u16* __restrict__ ol) {
    int i = (blockIdx.x * blockDim.x + threadIdx.x) * 4;
    f32x4 x = *(const f32x4*)(om + i);
    ushort4 h, l;
    u16 t;
    t = f2bf(x.x); h.x = t; l.x = f2bf(x.x - bf2f(t));
    t = f2bf(x.y); h.y = t; l.y = f2bf(x.y - bf2f(t));
    t = f2bf(x.z); h.z = t; l.z = f2bf(x.z - bf2f(t));
    t = f2bf(x.w); h.w = t; l.w = f2bf(x.w - bf2f(t));
    *(ushort4*)(oh + i) = h;
    *(ushort4*)(ol + i) = l;
}

// ---------------------------------------------------------------------------
// Kernel 2: Stage A v3 — R5's block-shared LDS structure, but the step is
// reordered to hide staging latency:
//   R5:  stage(k) -> barrier[drains stage(k): ~400cy exposed] -> ds_read -> MFMA -> barrier
//   v3:  ds_read(k) -> barrier[reads reg-resident; single buffer safe]
//        -> issue stage(k+1) + X(k+1) convert/ds_write -> MFMA(k)
//        -> barrier[drains stage(k+1), which had the MFMA phase to land]
// X global loads register-prefetched 2 steps ahead (consume-before-reload,
// single static buffer). Same LDS (37 KB), same 4 blocks/CU, 2 barriers/step.
// ---------------------------------------------------------------------------
__global__ __launch_bounds__(256, 4)
void k_stageA(const float* __restrict__ Hs, const float* __restrict__ Ws,
              const u16* __restrict__ Oh, const u16* __restrict__ Ol,
              u16* __restrict__ phiH, u16* __restrict__ phiW,
              float* __restrict__ emH, float* __restrict__ emW)
{
    __shared__ alignas(16) u16 Ah[32 * 32];
    __shared__ alignas(16) u16 Al[32 * 32];
    __shared__ alignas(16) u16 Bh[256 * 32];
    __shared__ alignas(16) u16 Bl[256 * 32];
    __shared__ float redmax[4][32];

    const int tid  = threadIdx.x;
    const int lane = tid & 63;
    const int wid  = tid >> 6;

    const float* __restrict__ X;
    u16* __restrict__ phi;
    float* __restrict__ em;
    int row0;
    if (blockIdx.x < NN / 32) {
        X = Hs; phi = phiH; em = emH; row0 = blockIdx.x * 32;
    } else {
        X = Ws; phi = phiW; em = emW; row0 = (blockIdx.x - NN / 32) * 32;
    }

    f32x4 acc[2][4];
#pragma unroll
    for (int m = 0; m < 2; ++m)
#pragma unroll
        for (int n = 0; n < 4; ++n) acc[m][n] = f32x4{0.f, 0.f, 0.f, 0.f};

    // A staging: thread loads float4 (row arow, fp32 cols acol..acol+3)
    const int arow = tid >> 3;           // 0..31
    const int acol = (tid & 7) * 4;      // 0,4,..,28
    const float* __restrict__ xrow = X + (long)(row0 + arow) * DD;
    const int a_idx = arow * 32 + (acol ^ (((arow >> 1) & 3) << 3));

    const int r16 = lane & 15;
    const int h8  = (lane >> 4) << 3;
    int aoffs[2], boffs[4];
#pragma unroll
    for (int m = 0; m < 2; ++m) {
        int row = m * 16 + r16;
        aoffs[m] = row * 32 + (h8 ^ (((row >> 1) & 3) << 3));
    }
#pragma unroll
    for (int n = 0; n < 4; ++n) {
        int row = wid * 64 + n * 16 + r16;
        boffs[n] = row * 32 + (h8 ^ (((row >> 1) & 3) << 3));
    }

    auto stageO = [&](int k0) {
#pragma unroll
        for (int s = 0; s < 4; ++s) {
            const int c    = s * 256 + tid;
            const int brow = c >> 2;
            const int scol = k0 + (((c & 3) << 3) ^ (((brow >> 1) & 3) << 3));
            gload_lds16(Oh + brow * DD + scol, Bh + (s * 256 + wid * 64) * 8);
            gload_lds16(Ol + brow * DD + scol, Bl + (s * 256 + wid * 64) * 8);
        }
    };
    auto convwrite = [&](const f32x4& x) {
        u32x2 ph, pl;
#pragma unroll
        for (int j = 0; j < 2; ++j) {
            u16 h0 = f2bf(x[2 * j]);
            u16 h1 = f2bf(x[2 * j + 1]);
            u16 l0 = f2bf(x[2 * j] - bf2f(h0));
            u16 l1 = f2bf(x[2 * j + 1] - bf2f(h1));
            ph[j] = (u32)h0 | ((u32)h1 << 16);
            pl[j] = (u32)l0 | ((u32)l1 << 16);
        }
        *(u32x2*)(Ah + a_idx) = ph;
        *(u32x2*)(Al + a_idx) = pl;
    };

    // prologue: tile 0 fully into LDS; prefetch X(1) to regs
    stageO(0);
    f32x4 x0 = *(const f32x4*)(xrow + acol);
    convwrite(x0);
    f32x4 xN = *(const f32x4*)(xrow + 32 + acol);   // X for ks=1
    __syncthreads();   // tile 0 ready (one-time full drain)

    for (int ks = 0; ks < 32; ++ks) {
        // 1) read tile-ks fragments into registers
        bf16x8 fah[2], fal[2], fbh[4], fbl[4];
#pragma unroll
        for (int m = 0; m < 2; ++m) {
            fah[m] = ldfrag(Ah + aoffs[m]);
            fal[m] = ldfrag(Al + aoffs[m]);
        }
#pragma unroll
        for (int n = 0; n < 4; ++n) {
            fbh[n] = ldfrag(Bh + boffs[n]);
            fbl[n] = ldfrag(Bl + boffs[n]);
        }
        // 2) all waves' reads complete -> single LDS buffer safe to overwrite
        __syncthreads();
        // 3) issue next tile's staging NOW (lands during MFMA phase)
        if (ks + 1 < 32) {
            stageO((ks + 1) * 32);
            convwrite(xN);                                   // X(ks+1) -> LDS
        }
        if (ks + 2 < 32)
            xN = *(const f32x4*)(xrow + (ks + 2) * 32 + acol); // prefetch X(ks+2)
        // 4) MFMA on register-resident fragments (overlaps staged loads)
#pragma unroll
        for (int m = 0; m < 2; ++m)
#pragma unroll
            for (int n = 0; n < 4; ++n) {
                acc[m][n] = MFMA16(fah[m], fbh[n], acc[m][n]);
                acc[m][n] = MFMA16(fah[m], fbl[n], acc[m][n]);
                acc[m][n] = MFMA16(fal[m], fbh[n], acc[m][n]);
            }
        // 5) drain: staged loads had the whole MFMA+convert phase to land
        __syncthreads();
    }

    // row max: lane-local over n, then across the 16 lanes sharing a row
#pragma unroll
    for (int m = 0; m < 2; ++m) {
#pragma unroll
        for (int i = 0; i < 4; ++i) {
            float v = fmaxf(fmaxf(acc[m][0][i], acc[m][1][i]),
                            fmaxf(acc[m][2][i], acc[m][3][i]));
            v = fmaxf(v, __shfl_xor(v, 1));
            v = fmaxf(v, __shfl_xor(v, 2));
            v = fmaxf(v, __shfl_xor(v, 4));
            v = fmaxf(v, __shfl_xor(v, 8));
            if (r16 == 0) redmax[wid][m * 16 + ((lane >> 4) << 2) + i] = v;
        }
    }
    __syncthreads();
    if (tid < 32) {
        float fm = fmaxf(fmaxf(redmax[0][tid], redmax[1][tid]),
                         fmaxf(redmax[2][tid], redmax[3][tid]));
        // em = exp(-clamp(max)) so stage B epilogue needs no log/exp
        em[row0 + tid] = __expf(fminf(fmaxf(-fm, -87.f), 87.f));
    }
#pragma unroll
    for (int m = 0; m < 2; ++m) {
#pragma unroll
        for (int i = 0; i < 4; ++i) {
            const int rl = m * 16 + ((lane >> 4) << 2) + i;
            const float fm = fmaxf(fmaxf(redmax[0][rl], redmax[1][rl]),
                                   fmaxf(redmax[2][rl], redmax[3][rl]));
#pragma unroll
            for (int n = 0; n < 4; ++n) {
                float p   = acc[m][n][i];
                float ph_ = (__expf(p - fm) + 1e-6f) * 0.0625f;
                phi[(long)(row0 + rl) * MM + wid * 64 + n * 16 + r16] = f2bf(ph_);
            }
        }
    }
}

// ---------------------------------------------------------------------------
// Kernel 3: Stage B — rf = phi_h @ phi_w^T (K=256), epilogue
//   out = rf' / (rf' + eh*ew),  rf' = rf + 1e-10
// [R11 verbatim — 106us vs 81us write floor; scheduling theories exhausted]
// ---------------------------------------------------------------------------
__global__ __launch_bounds__(256, 4)
void k_stageB(const u16* __restrict__ PH, const u16* __restrict__ PW,
              const float* __restrict__ EH, const float* __restrict__ EW,
              float* __restrict__ out)
{
    // union: K-loop staging (32 KB) | epilogue f32 tile 64x130 (33.28 KB)
    __shared__ alignas(16) unsigned char smem_raw[64 * 130 * 4];
    u16* const As = (u16*)smem_raw;
    u16* const Bs = As + 128 * 64;
    float* const ftile = (float*)smem_raw;
    const int FST = 130;

    const int tid  = threadIdx.x;
    const int lane = tid & 63;
    const int wid  = tid >> 6;
    const int bm   = blockIdx.x >> 6;   // 0..127
    const int bn   = blockIdx.x & 63;   // 0..63
    const int row0 = bm * 128, col0 = bn * 128;
    const int wr   = wid >> 1, wc = wid & 1;
    const int r16  = lane & 15;
    const int h8   = (lane >> 4) << 3;

    f32x4 acc[4][4];
#pragma unroll
    for (int m = 0; m < 4; ++m)
#pragma unroll
        for (int n = 0; n < 4; ++n) acc[m][n] = f32x4{0.f, 0.f, 0.f, 0.f};

    int aoffs[2][4], boffs[2][4];
#pragma unroll
    for (int sl = 0; sl < 2; ++sl) {
#pragma unroll
        for (int m = 0; m < 4; ++m) {
            int row = wr * 64 + m * 16 + r16;
            aoffs[sl][m] = row * 64 + (((((sl * 32 + h8) << 1)) ^ ((row & 7) << 4)) >> 1);
        }
#pragma unroll
        for (int n = 0; n < 4; ++n) {
            int row = wc * 64 + n * 16 + r16;
            boffs[sl][n] = row * 64 + (((((sl * 32 + h8) << 1)) ^ ((row & 7) << 4)) >> 1);
        }
    }

    for (int ks = 0; ks < 4; ++ks) {
        const int k0 = ks * 64;
#pragma unroll
        for (int s = 0; s < 4; ++s) {
            const int c    = s * 256 + tid;
            const int row  = c >> 3;
            const int cbl  = ((c & 7) << 4) ^ ((row & 7) << 4);
            const int scol = k0 + (cbl >> 1);
            gload_lds16(PH + (long)(row0 + row) * MM + scol, As + (s * 256 + wid * 64) * 8);
            gload_lds16(PW + (long)(col0 + row) * MM + scol, Bs + (s * 256 + wid * 64) * 8);
        }
        __syncthreads();
#pragma unroll
        for (int sl = 0; sl < 2; ++sl) {
            bf16x8 fa[4], fb[4];
#pragma unroll
            for (int m = 0; m < 4; ++m) fa[m] = ldfrag(As + aoffs[sl][m]);
#pragma unroll
            for (int n = 0; n < 4; ++n) fb[n] = ldfrag(Bs + boffs[sl][n]);
#pragma unroll
            for (int m = 0; m < 4; ++m)
#pragma unroll
                for (int n = 0; n < 4; ++n)
                    acc[m][n] = MFMA16(fa[m], fb[n], acc[m][n]);
        }
        __syncthreads();
    }
    // K-loop's final __syncthreads drained everything: As/Bs reads retired.

    // epilogue: out = rf' / (rf' + eh*ew). 2 passes of 64 rows; LDS-only
    // synchronization (lgkmcnt + raw s_barrier) -> NT stores never drained.
    float ew_[4];
#pragma unroll
    for (int n = 0; n < 4; ++n) ew_[n] = EW[col0 + wc * 64 + n * 16 + r16];

#pragma unroll
    for (int mm = 0; mm < 2; ++mm) {
        if (mm == 1) {
            asm volatile("s_waitcnt lgkmcnt(0)" ::: "memory");
            __builtin_amdgcn_s_barrier();
        }
#pragma unroll
        for (int ms = 0; ms < 2; ++ms) {
            const int m = 2 * mm + ms;
#pragma unroll
            for (int i = 0; i < 4; ++i) {
                const int lr   = wr * 32 + ms * 16 + ((lane >> 4) << 2) + i; // 0..63
                const int grow = row0 + wr * 64 + m * 16 + ((lane >> 4) << 2) + i;
                const float eh = EH[grow];
#pragma unroll
                for (int n = 0; n < 4; ++n) {
                    float rf = acc[m][n][i] + 1e-10f;
                    float t  = eh * ew_[n];
                    float o  = rf * __builtin_amdgcn_rcpf(rf + t);
                    ftile[lr * FST + wc * 64 + n * 16 + r16] = o;
                }
            }
        }
        asm volatile("s_waitcnt lgkmcnt(0)" ::: "memory");
        __builtin_amdgcn_s_barrier();
#pragma unroll
        for (int p = 0; p < 8; ++p) {
            const int r = p * 8 + (tid >> 5);        // 0..63 local row
            const int c = (tid & 31) * 4;            // 0..124
            f32x4 v = *(const f32x4*)&ftile[r * FST + c];
            const int grow = row0 + (r >> 5) * 64 + (2 * mm + ((r >> 4) & 1)) * 16 + (r & 15);
            __builtin_nontemporal_store(
                v, (f32x4*)(out + (long)grow * KK + col0 + c));
        }
    }
}

// ---------------------------------------------------------------------------
extern "C" void kernel_launch(void* const* d_in, const int* in_sizes, int n_in,
                              void* d_out, int out_size, void* d_ws, size_t ws_size,
                              hipStream_t stream) {
    (void)in_sizes; (void)n_in; (void)out_size; (void)ws_size;
    const float* H  = (const float*)d_in[0];
    const float* W  = (const float*)d_in[1];
    const float* Om = (const float*)d_in[2];
    float* out = (float*)d_out;

    char* ws   = (char*)d_ws;
    u16*  phiH = (u16*)ws;                                       // 8 MB
    u16*  phiW = (u16*)(ws + (size_t)NN * MM * 2);               // 4 MB
    float* emh = (float*)(ws + (size_t)(NN + KK) * MM * 2);      // 64 KB
    float* emw = emh + NN;                                       // 32 KB
    u16*  oh   = (u16*)(emw + KK);                               // 512 KB
    u16*  ol   = oh + MM * DD;                                   // 512 KB

    k_conv<<<(MM * DD) / 1024, 256, 0, stream>>>(Om, oh, ol);
    k_stageA<<<(NN + KK) / 32, 256, 0, stream>>>(H, W, oh, ol, phiH, phiW, emh, emw);
    k_stageB<<<(NN / 128) * (KK / 128), 256, 0, stream>>>(phiH, phiW, emh, emw, out);
}

// Round 17
// 174.693 us; speedup vs baseline: 12.2513x; 1.0257x over previous
//
#include <hip/hip_runtime.h>

#define DD 1024   // hidden size
#define MM 256    // random features
#define NN 16384  // hidden states
#define KK 8192   // weight rows

typedef float f32x4 __attribute__((ext_vector_type(4)));
typedef unsigned int u32x4 __attribute__((ext_vector_type(4)));
typedef unsigned int u32x2 __attribute__((ext_vector_type(2)));
typedef __bf16 bf16x8 __attribute__((ext_vector_type(8)));
typedef unsigned short u16;
typedef unsigned int u32;

static __device__ __forceinline__ u16 f2bf(float f) {
    u32 u = __builtin_bit_cast(u32, f);
    u32 r = u + 0x7fffu + ((u >> 16) & 1u);
    return (u16)(r >> 16);
}
static __device__ __forceinline__ float bf2f(u16 h) {
    u32 u = ((u32)h) << 16;
    return __builtin_bit_cast(float, u);
}

static __device__ __forceinline__ void gload_lds16(const void* g, void* l) {
    __builtin_amdgcn_global_load_lds(
        (const __attribute__((address_space(1))) u32*)g,
        (__attribute__((address_space(3))) u32*)l, 16, 0, 0);
}

static __device__ __forceinline__ bf16x8 ldfrag(const u16* p) {
    return __builtin_bit_cast(bf16x8, *(const u32x4*)p);
}

#define MFMA16(a, b, c) __builtin_amdgcn_mfma_f32_16x16x32_bf16((a), (b), (c), 0, 0, 0)

// ---------------------------------------------------------------------------
// Kernel 1: omega fp32 -> (hi, lo) bf16 split   [R5 verbatim]
// ---------------------------------------------------------------------------
__global__ void k_conv(const float* __restrict__ om, u16* __restrict__ oh,
                       u16* __restrict__ ol) {
    int i = (blockIdx.x * blockDim.x + threadIdx.x) * 4;
    f32x4 x = *(const f32x4*)(om + i);
    ushort4 h, l;
    u16 t;
    t = f2bf(x.x); h.x = t; l.x = f2bf(x.x - bf2f(t));
    t = f2bf(x.y); h.y = t; l.y = f2bf(x.y - bf2f(t));
    t = f2bf(x.z); h.z = t; l.z = f2bf(x.z - bf2f(t));
    t = f2bf(x.w); h.w = t; l.w = f2bf(x.w - bf2f(t));
    *(ushort4*)(oh + i) = h;
    *(ushort4*)(ol + i) = l;
}

// ---------------------------------------------------------------------------
// Kernel 2: Stage A v3 [R16 verbatim — equal-best]
// ---------------------------------------------------------------------------
__global__ __launch_bounds__(256, 4)
void k_stageA(const float* __restrict__ Hs, const float* __restrict__ Ws,
              const u16* __restrict__ Oh, const u16* __restrict__ Ol,
              u16* __restrict__ phiH, u16* __restrict__ phiW,
              float* __restrict__ emH, float* __restrict__ emW)
{
    __shared__ alignas(16) u16 Ah[32 * 32];
    __shared__ alignas(16) u16 Al[32 * 32];
    __shared__ alignas(16) u16 Bh[256 * 32];
    __shared__ alignas(16) u16 Bl[256 * 32];
    __shared__ float redmax[4][32];

    const int tid  = threadIdx.x;
    const int lane = tid & 63;
    const int wid  = tid >> 6;

    const float* __restrict__ X;
    u16* __restrict__ phi;
    float* __restrict__ em;
    int row0;
    if (blockIdx.x < NN / 32) {
        X = Hs; phi = phiH; em = emH; row0 = blockIdx.x * 32;
    } else {
        X = Ws; phi = phiW; em = emW; row0 = (blockIdx.x - NN / 32) * 32;
    }

    f32x4 acc[2][4];
#pragma unroll
    for (int m = 0; m < 2; ++m)
#pragma unroll
        for (int n = 0; n < 4; ++n) acc[m][n] = f32x4{0.f, 0.f, 0.f, 0.f};

    const int arow = tid >> 3;           // 0..31
    const int acol = (tid & 7) * 4;      // 0,4,..,28
    const float* __restrict__ xrow = X + (long)(row0 + arow) * DD;
    const int a_idx = arow * 32 + (acol ^ (((arow >> 1) & 3) << 3));

    const int r16 = lane & 15;
    const int h8  = (lane >> 4) << 3;
    int aoffs[2], boffs[4];
#pragma unroll
    for (int m = 0; m < 2; ++m) {
        int row = m * 16 + r16;
        aoffs[m] = row * 32 + (h8 ^ (((row >> 1) & 3) << 3));
    }
#pragma unroll
    for (int n = 0; n < 4; ++n) {
        int row = wid * 64 + n * 16 + r16;
        boffs[n] = row * 32 + (h8 ^ (((row >> 1) & 3) << 3));
    }

    auto stageO = [&](int k0) {
#pragma unroll
        for (int s = 0; s < 4; ++s) {
            const int c    = s * 256 + tid;
            const int brow = c >> 2;
            const int scol = k0 + (((c & 3) << 3) ^ (((brow >> 1) & 3) << 3));
            gload_lds16(Oh + brow * DD + scol, Bh + (s * 256 + wid * 64) * 8);
            gload_lds16(Ol + brow * DD + scol, Bl + (s * 256 + wid * 64) * 8);
        }
    };
    auto convwrite = [&](const f32x4& x) {
        u32x2 ph, pl;
#pragma unroll
        for (int j = 0; j < 2; ++j) {
            u16 h0 = f2bf(x[2 * j]);
            u16 h1 = f2bf(x[2 * j + 1]);
            u16 l0 = f2bf(x[2 * j] - bf2f(h0));
            u16 l1 = f2bf(x[2 * j + 1] - bf2f(h1));
            ph[j] = (u32)h0 | ((u32)h1 << 16);
            pl[j] = (u32)l0 | ((u32)l1 << 16);
        }
        *(u32x2*)(Ah + a_idx) = ph;
        *(u32x2*)(Al + a_idx) = pl;
    };

    stageO(0);
    f32x4 x0 = *(const f32x4*)(xrow + acol);
    convwrite(x0);
    f32x4 xN = *(const f32x4*)(xrow + 32 + acol);
    __syncthreads();

    for (int ks = 0; ks < 32; ++ks) {
        bf16x8 fah[2], fal[2], fbh[4], fbl[4];
#pragma unroll
        for (int m = 0; m < 2; ++m) {
            fah[m] = ldfrag(Ah + aoffs[m]);
            fal[m] = ldfrag(Al + aoffs[m]);
        }
#pragma unroll
        for (int n = 0; n < 4; ++n) {
            fbh[n] = ldfrag(Bh + boffs[n]);
            fbl[n] = ldfrag(Bl + boffs[n]);
        }
        __syncthreads();
        if (ks + 1 < 32) {
            stageO((ks + 1) * 32);
            convwrite(xN);
        }
        if (ks + 2 < 32)
            xN = *(const f32x4*)(xrow + (ks + 2) * 32 + acol);
#pragma unroll
        for (int m = 0; m < 2; ++m)
#pragma unroll
            for (int n = 0; n < 4; ++n) {
                acc[m][n] = MFMA16(fah[m], fbh[n], acc[m][n]);
                acc[m][n] = MFMA16(fah[m], fbl[n], acc[m][n]);
                acc[m][n] = MFMA16(fal[m], fbh[n], acc[m][n]);
            }
        __syncthreads();
    }

#pragma unroll
    for (int m = 0; m < 2; ++m) {
#pragma unroll
        for (int i = 0; i < 4; ++i) {
            float v = fmaxf(fmaxf(acc[m][0][i], acc[m][1][i]),
                            fmaxf(acc[m][2][i], acc[m][3][i]));
            v = fmaxf(v, __shfl_xor(v, 1));
            v = fmaxf(v, __shfl_xor(v, 2));
            v = fmaxf(v, __shfl_xor(v, 4));
            v = fmaxf(v, __shfl_xor(v, 8));
            if (r16 == 0) redmax[wid][m * 16 + ((lane >> 4) << 2) + i] = v;
        }
    }
    __syncthreads();
    if (tid < 32) {
        float fm = fmaxf(fmaxf(redmax[0][tid], redmax[1][tid]),
                         fmaxf(redmax[2][tid], redmax[3][tid]));
        em[row0 + tid] = __expf(fminf(fmaxf(-fm, -87.f), 87.f));
    }
#pragma unroll
    for (int m = 0; m < 2; ++m) {
#pragma unroll
        for (int i = 0; i < 4; ++i) {
            const int rl = m * 16 + ((lane >> 4) << 2) + i;
            const float fm = fmaxf(fmaxf(redmax[0][rl], redmax[1][rl]),
                                   fmaxf(redmax[2][rl], redmax[3][rl]));
#pragma unroll
            for (int n = 0; n < 4; ++n) {
                float p   = acc[m][n][i];
                float ph_ = (__expf(p - fm) + 1e-6f) * 0.0625f;
                phi[(long)(row0 + rl) * MM + wid * 64 + n * 16 + r16] = f2bf(ph_);
            }
        }
    }
}

// ---------------------------------------------------------------------------
// Kernel 3: Stage B v2 — WIDE TILE 64x256 (was 128x128). Each output row of
// the tile is now 1 KB contiguous (256 cols x 4B), written by ONE full-wave
// NT store (64 lanes x 16B) — doubles the HBM write segment size, halves
// segment count (the 512B-segment scatter was the write-efficiency gap).
// Wave layout: 4 waves side-by-side along columns, each 64 rows x 64 cols
// (same acc[4][4] and swizzle as before; rows still 128B in LDS).
//   out = rf' / (rf' + eh*ew),  rf' = rf + 1e-10
// ---------------------------------------------------------------------------
__global__ __launch_bounds__(256, 3)
void k_stageB(const u16* __restrict__ PH, const u16* __restrict__ PW,
              const float* __restrict__ EH, const float* __restrict__ EW,
              float* __restrict__ out)
{
    // union: K-loop staging As 8KB + Bs 32KB | epilogue ftile 32x260 f32 (33.3KB)
    __shared__ alignas(16) unsigned char smem_raw[40 * 1024];
    u16* const As = (u16*)smem_raw;              // 64 rows x 64 cols
    u16* const Bs = As + 64 * 64;                // 256 rows x 64 cols
    float* const ftile = (float*)smem_raw;
    const int FST = 260;                         // 32 x 260 f32, pad 4

    const int tid  = threadIdx.x;
    const int lane = tid & 63;
    const int wid  = tid >> 6;
    const int bm   = blockIdx.x >> 5;   // 0..255
    const int bn   = blockIdx.x & 31;   // 0..31
    const int row0 = bm * 64, col0 = bn * 256;
    const int r16  = lane & 15;
    const int h8   = (lane >> 4) << 3;

    f32x4 acc[4][4];
#pragma unroll
    for (int m = 0; m < 4; ++m)
#pragma unroll
        for (int n = 0; n < 4; ++n) acc[m][n] = f32x4{0.f, 0.f, 0.f, 0.f};

    // fragment offsets (u16 units); rows 128B, byte swizzle ((row&7)<<4)
    int aoffs[2][4], boffs[2][4];
#pragma unroll
    for (int sl = 0; sl < 2; ++sl) {
#pragma unroll
        for (int m = 0; m < 4; ++m) {
            int row = m * 16 + r16;                      // A row 0..63
            aoffs[sl][m] = row * 64 + ((sl * 32 + h8) ^ ((row & 7) << 3));
        }
#pragma unroll
        for (int n = 0; n < 4; ++n) {
            int row = wid * 64 + n * 16 + r16;           // B row 0..255
            boffs[sl][n] = row * 64 + ((sl * 32 + h8) ^ ((row & 7) << 3));
        }
    }

    for (int ks = 0; ks < 4; ++ks) {
        const int k0 = ks * 64;
        // A panel: 64 rows x 64 k = 8KB -> 2 gl_lds/thread
#pragma unroll
        for (int s = 0; s < 2; ++s) {
            const int c    = s * 256 + tid;
            const int row  = c >> 3;
            const int scol = k0 + ((((c & 7) << 3)) ^ ((row & 7) << 3));
            gload_lds16(PH + (long)(row0 + row) * MM + scol, As + c * 8);
        }
        // B panel: 256 rows x 64 k = 32KB -> 8 gl_lds/thread
#pragma unroll
        for (int s = 0; s < 8; ++s) {
            const int c    = s * 256 + tid;
            const int row  = c >> 3;
            const int scol = k0 + ((((c & 7) << 3)) ^ ((row & 7) << 3));
            gload_lds16(PW + (long)(col0 + row) * MM + scol, Bs + c * 8);
        }
        __syncthreads();
#pragma unroll
        for (int sl = 0; sl < 2; ++sl) {
            bf16x8 fa[4], fb[4];
#pragma unroll
            for (int m = 0; m < 4; ++m) fa[m] = ldfrag(As + aoffs[sl][m]);
#pragma unroll
            for (int n = 0; n < 4; ++n) fb[n] = ldfrag(Bs + boffs[sl][n]);
#pragma unroll
            for (int m = 0; m < 4; ++m)
#pragma unroll
                for (int n = 0; n < 4; ++n)
                    acc[m][n] = MFMA16(fa[m], fb[n], acc[m][n]);
        }
        __syncthreads();
    }
    // K-loop's final __syncthreads drained everything: As/Bs reads retired.

    // epilogue: 2 passes of 32 rows x 256 cols through ftile; LDS-only sync.
    float ew_[4];
#pragma unroll
    for (int n = 0; n < 4; ++n) ew_[n] = EW[col0 + wid * 64 + n * 16 + r16];

#pragma unroll
    for (int mm = 0; mm < 2; ++mm) {
        if (mm == 1) {
            // WAR: pass-0 ftile ds_reads must retire before overwrite
            asm volatile("s_waitcnt lgkmcnt(0)" ::: "memory");
            __builtin_amdgcn_s_barrier();
        }
#pragma unroll
        for (int ms = 0; ms < 2; ++ms) {
            const int m = 2 * mm + ms;
#pragma unroll
            for (int i = 0; i < 4; ++i) {
                const int q    = ((lane >> 4) << 2) + i;       // 0..15
                const int lr   = ms * 16 + q;                  // 0..31 in pass
                const int grow = row0 + m * 16 + q;
                const float eh = EH[grow];
#pragma unroll
                for (int n = 0; n < 4; ++n) {
                    float rf = acc[m][n][i] + 1e-10f;
                    float t  = eh * ew_[n];
                    float o  = rf * __builtin_amdgcn_rcpf(rf + t);
                    ftile[lr * FST + wid * 64 + n * 16 + r16] = o;
                }
            }
        }
        // ds_writes visible to all waves (LDS only — no vmcnt drain)
        asm volatile("s_waitcnt lgkmcnt(0)" ::: "memory");
        __builtin_amdgcn_s_barrier();
        // readback + NT stores: one wave = one full 1KB output row
#pragma unroll
        for (int p = 0; p < 8; ++p) {
            const int r = p * 4 + wid;               // 0..31 local row
            const int c = lane * 4;                  // 0..252
            f32x4 v = *(const f32x4*)&ftile[r * FST + c];
            const int grow = row0 + mm * 32 + r;
            __builtin_nontemporal_store(
                v, (f32x4*)(out + (long)grow * KK + col0 + c));
        }
    }
}

// ---------------------------------------------------------------------------
extern "C" void kernel_launch(void* const* d_in, const int* in_sizes, int n_in,
                              void* d_out, int out_size, void* d_ws, size_t ws_size,
                              hipStream_t stream) {
    (void)in_sizes; (void)n_in; (void)out_size; (void)ws_size;
    const float* H  = (const float*)d_in[0];
    const float* W  = (const float*)d_in[1];
    const float* Om = (const float*)d_in[2];
    float* out = (float*)d_out;

    char* ws   = (char*)d_ws;
    u16*  phiH = (u16*)ws;                                       // 8 MB
    u16*  phiW = (u16*)(ws + (size_t)NN * MM * 2);               // 4 MB
    float* emh = (float*)(ws + (size_t)(NN + KK) * MM * 2);      // 64 KB
    float* emw = emh + NN;                                       // 32 KB
    u16*  oh   = (u16*)(emw + KK);                               // 512 KB
    u16*  ol   = oh + MM * DD;                                   // 512 KB

    k_conv<<<(MM * DD) / 1024, 256, 0, stream>>>(Om, oh, ol);
    k_stageA<<<(NN + KK) / 32, 256, 0, stream>>>(H, W, oh, ol, phiH, phiW, emh, emw);
    k_stageB<<<(NN / 64) * (KK / 256), 256, 0, stream>>>(phiH, phiW, emh, emw, out);
}